// Round 5
// baseline (119.722 us; speedup 1.0000x reference)
//
#include <hip/hip_runtime.h>
#include <hip/hip_bf16.h>

// Problem constants (EdgeQProj): B=64, N=64, E=512, OBJ_DIM=2048, Q_DIM=1024,
// HID=512, KS=8. M_edges = B*E = 32768.

using bf16x8 = __attribute__((ext_vector_type(8))) __bf16;
using f32x4  = __attribute__((ext_vector_type(4))) float;

__device__ __forceinline__ unsigned short f2bf(float f) {
    unsigned int u = __float_as_uint(f);
    unsigned int r = (u + 0x7FFFu + ((u >> 16) & 1u)) >> 16;  // RNE
    return (unsigned short)r;
}

__device__ __forceinline__ float bf2f(unsigned short s) {
    return __uint_as_float((unsigned int)s << 16);
}

__device__ __forceinline__ uint4 pack8(float4 a, float4 b) {
    union { unsigned short us[8]; uint4 u4; } r;
    r.us[0] = f2bf(a.x); r.us[1] = f2bf(a.y); r.us[2] = f2bf(a.z); r.us[3] = f2bf(a.w);
    r.us[4] = f2bf(b.x); r.us[5] = f2bf(b.y); r.us[6] = f2bf(b.z); r.us[7] = f2bf(b.w);
    return r.u4;
}

// ---------------------------------------------------------------------------
// 1) W_obj fp32 [2048][512] -> W_T bf16 [512][2048]  (tiled transpose)
__global__ __launch_bounds__(256) void cvt_bt(const float* __restrict__ W,
                                              unsigned short* __restrict__ WT) {
    __shared__ float lds[32][33];
    int k0 = blockIdx.x * 32, n0 = blockIdx.y * 32;
    int tx = threadIdx.x & 31, ty = threadIdx.x >> 5;  // ty 0..7
#pragma unroll
    for (int j = 0; j < 4; ++j)
        lds[ty + j * 8][tx] = W[(size_t)(k0 + ty + j * 8) * 512 + n0 + tx];
    __syncthreads();
#pragma unroll
    for (int j = 0; j < 4; ++j)
        WT[(size_t)(n0 + ty + j * 8) * 2048 + k0 + tx] = f2bf(lds[tx][ty + j * 8]);
}

// ---------------------------------------------------------------------------
// 2) GEMM1: node_h[4096][512](bf16) = relu(A_f32[4096][2048] @ W_T^T + b_obj)
//    BM=64 BN=64 BK=128, 256 thr (4 waves, 2x2), grid 512 = 2 blocks/CU.
//    Register-prefetch pipeline: step s+1's global loads issue between the
//    barrier and step s's MFMAs; vmcnt-wait lands at the next LDS write,
//    hidden under MFMA+ds_read. fp32->bf16 cast fused into staging.
//    LDS rows padded to 136 shorts -> 2-way bank aliasing (free).
#define LDK1 136
__global__ __launch_bounds__(256, 2) void gemm1(const float* __restrict__ A32,
                                                const unsigned short* __restrict__ BT,
                                                const float* __restrict__ bias,
                                                unsigned short* __restrict__ C) {
    __shared__ __align__(16) unsigned short Asm[64][LDK1];
    __shared__ __align__(16) unsigned short Bsm[64][LDK1];

    // XCD swizzle: grid 512 (%8==0, bijective). XCD x -> m-panels [x*8,x*8+8)
    // (4MB A slice) x all 8 n-panels + full B (2MB) ~ L2-resident.
    int bid = blockIdx.x;
    int swz = (bid & 7) * 64 + (bid >> 3);
    int by = swz >> 3, bx = swz & 7;
    int m0 = by * 64, n0 = bx * 64;

    int t = threadIdx.x;
    int lane = t & 63, w = t >> 6;
    int wm = w >> 1, wn = w & 1;              // wave grid 2x2
    int l15 = lane & 15, l16 = lane >> 4;

    int srow = t >> 2, skc = (t & 3) * 32;    // staging: row, k-chunk of 32
    const float*          apB = A32 + (size_t)(m0 + srow) * 2048 + skc;
    const unsigned short* bpB = BT  + (size_t)(n0 + srow) * 2048 + skc;

    float4 ar[8];
    uint4  br[4];
#pragma unroll
    for (int j = 0; j < 8; ++j) ar[j] = *(const float4*)(apB + j * 4);
#pragma unroll
    for (int j = 0; j < 4; ++j) br[j] = *(const uint4*)(bpB + j * 8);

    f32x4 acc[2][2];
#pragma unroll
    for (int i = 0; i < 2; ++i)
#pragma unroll
        for (int j = 0; j < 2; ++j) acc[i][j] = (f32x4){0.f, 0.f, 0.f, 0.f};

    for (int s = 0; s < 16; ++s) {
        // convert + LDS write of the prefetched tile
#pragma unroll
        for (int j = 0; j < 4; ++j)
            *(uint4*)(&Asm[srow][skc + j * 8]) = pack8(ar[2 * j], ar[2 * j + 1]);
#pragma unroll
        for (int j = 0; j < 4; ++j)
            *(uint4*)(&Bsm[srow][skc + j * 8]) = br[j];
        __syncthreads();

        // issue next step's loads (completion awaited only at next LDS write)
        if (s < 15) {
            const float*          ap = apB + (s + 1) * 128;
            const unsigned short* bp = bpB + (s + 1) * 128;
#pragma unroll
            for (int j = 0; j < 8; ++j) ar[j] = *(const float4*)(ap + j * 4);
#pragma unroll
            for (int j = 0; j < 4; ++j) br[j] = *(const uint4*)(bp + j * 8);
        }

        // compute: 4 ksubs x (2x2) MFMAs
#pragma unroll
        for (int ks = 0; ks < 4; ++ks) {
            bf16x8 a0 = *(const bf16x8*)(&Asm[wm * 32 + l15][ks * 32 + l16 * 8]);
            bf16x8 a1 = *(const bf16x8*)(&Asm[wm * 32 + 16 + l15][ks * 32 + l16 * 8]);
            bf16x8 b0 = *(const bf16x8*)(&Bsm[wn * 32 + l15][ks * 32 + l16 * 8]);
            bf16x8 b1 = *(const bf16x8*)(&Bsm[wn * 32 + 16 + l15][ks * 32 + l16 * 8]);
            acc[0][0] = __builtin_amdgcn_mfma_f32_16x16x32_bf16(a0, b0, acc[0][0], 0, 0, 0);
            acc[0][1] = __builtin_amdgcn_mfma_f32_16x16x32_bf16(a0, b1, acc[0][1], 0, 0, 0);
            acc[1][0] = __builtin_amdgcn_mfma_f32_16x16x32_bf16(a1, b0, acc[1][0], 0, 0, 0);
            acc[1][1] = __builtin_amdgcn_mfma_f32_16x16x32_bf16(a1, b1, acc[1][1], 0, 0, 0);
        }
        __syncthreads();
    }

    // epilogue: bias + relu -> bf16; D layout col=lane&15, row=(lane>>4)*4+j
#pragma unroll
    for (int fm = 0; fm < 2; ++fm)
#pragma unroll
        for (int fn = 0; fn < 2; ++fn) {
            int col = n0 + wn * 32 + fn * 16 + l15;
            float bv = bias[col];
#pragma unroll
            for (int j = 0; j < 4; ++j) {
                int row = m0 + wm * 32 + fm * 16 + l16 * 4 + j;
                float v = acc[fm][fn][j] + bv;
                C[(size_t)row * 512 + col] = f2bf(v > 0.f ? v : 0.f);
            }
        }
}

// ---------------------------------------------------------------------------
// 3) GEMM2 (fused fp32->bf16 MFMA, single-pass W_q):
//    part[z][64][4096] = q[64][k0:k0+128] @ W_q[k0:k0+128][c0:c0+128]
//    grid (32 colblocks, 8 ksplits) = 256 blocks x 256 thr (4 waves).
#define LDK2 136
__global__ __launch_bounds__(256) void gemm2(const float* __restrict__ qf,
                                             const float* __restrict__ Wq,
                                             float* __restrict__ part) {
    __shared__ __align__(16) unsigned short Asm[64][LDK2];   // q tile  [m][k]
    __shared__ __align__(16) unsigned short Bsm[128][LDK2];  // W tile  [c][k]

    int t = threadIdx.x;
    int lane = t & 63, w = t >> 6;          // 4 waves, wave owns 32 cols
    int l15 = lane & 15, l16 = lane >> 4;
    int c0 = blockIdx.x * 128;
    int k0 = blockIdx.y * 128;

    // ---- stage A: q[64][k0:k0+128] fp32 -> bf16 ----
#pragma unroll
    for (int j = 0; j < 4; ++j) {
        int g = t + j * 256;                 // 1024 chunks of 8k
        int row = g >> 4, kc = g & 15;
        const float* src = qf + (size_t)row * 1024 + k0 + kc * 8;
        float4 v0 = *(const float4*)(src);
        float4 v1 = *(const float4*)(src + 4);
        *(uint4*)(&Asm[row][kc * 8]) = pack8(v0, v1);
    }
    // ---- stage B: W_q[k0:k0+128][c0:c0+128] fp32 -> bf16, transposed ----
#pragma unroll
    for (int j = 0; j < 2; ++j) {
        int g = t + j * 256;                 // 512 units of 8k x 4c
        int kg = g >> 5, cg = g & 31;
        f32x4 wv[8];
#pragma unroll
        for (int kk = 0; kk < 8; ++kk)
            wv[kk] = *(const f32x4*)(Wq + (size_t)(k0 + kg * 8 + kk) * 4096 + c0 + cg * 4);
#pragma unroll
        for (int cc = 0; cc < 4; ++cc) {
            union { unsigned short us[8]; uint4 u4; } p;
#pragma unroll
            for (int kk = 0; kk < 8; ++kk) p.us[kk] = f2bf(wv[kk][cc]);
            *(uint4*)(&Bsm[cg * 4 + cc][kg * 8]) = p.u4;
        }
    }
    __syncthreads();

    // ---- MFMA: wave w covers cols [w*32, w*32+32); 4m x 2n x 4k frags ----
    f32x4 acc[4][2];
#pragma unroll
    for (int i = 0; i < 4; ++i)
#pragma unroll
        for (int j = 0; j < 2; ++j) acc[i][j] = (f32x4){0.f, 0.f, 0.f, 0.f};

#pragma unroll
    for (int ks = 0; ks < 4; ++ks) {
        bf16x8 bfr[2];
#pragma unroll
        for (int jn = 0; jn < 2; ++jn)
            bfr[jn] = *(const bf16x8*)(&Bsm[w * 32 + jn * 16 + l15][ks * 32 + l16 * 8]);
#pragma unroll
        for (int i = 0; i < 4; ++i) {
            bf16x8 afr = *(const bf16x8*)(&Asm[i * 16 + l15][ks * 32 + l16 * 8]);
            acc[i][0] = __builtin_amdgcn_mfma_f32_16x16x32_bf16(afr, bfr[0], acc[i][0], 0, 0, 0);
            acc[i][1] = __builtin_amdgcn_mfma_f32_16x16x32_bf16(afr, bfr[1], acc[i][1], 0, 0, 0);
        }
    }

    // ---- write partials ----
    float* pz = part + (size_t)blockIdx.y * 262144;
#pragma unroll
    for (int i = 0; i < 4; ++i)
#pragma unroll
        for (int jn = 0; jn < 2; ++jn) {
            int col = c0 + w * 32 + jn * 16 + l15;
#pragma unroll
            for (int j = 0; j < 4; ++j) {
                int row = i * 16 + l16 * 4 + j;
                pz[(size_t)row * 4096 + col] = acc[i][jn][j];
            }
        }
}

// 4) reduce partials + bias + relu -> q_h[64][4096]
__global__ __launch_bounds__(256) void finish_q(const float* __restrict__ part,
                                                const float* __restrict__ bq,
                                                float* __restrict__ q_h) {
    int base = (blockIdx.x * 256 + threadIdx.x) * 4;
    f32x4 a = (f32x4){0.f, 0.f, 0.f, 0.f};
#pragma unroll
    for (int s = 0; s < 8; ++s) a += *(const f32x4*)(part + (size_t)s * 262144 + base);
    f32x4 bb = *(const f32x4*)(bq + (base & 4095));
#pragma unroll
    for (int j = 0; j < 4; ++j) {
        float v = a[j] + bb[j];
        a[j] = v > 0.f ? v : 0.f;
    }
    *(f32x4*)(q_h + base) = a;
}

// 5) inv_norm[b][k] = 1/sqrt(sum_h q_h[b][h*8+k]^2)
__global__ __launch_bounds__(256) void norms_k(const float* __restrict__ q_h,
                                               float* __restrict__ inv_norm) {
    __shared__ float red[4][8];
    int b = blockIdx.x, t = threadIdx.x;
    const float* row = q_h + (size_t)b * 4096 + t * 16;
    float sq[8] = {0.f, 0.f, 0.f, 0.f, 0.f, 0.f, 0.f, 0.f};
#pragma unroll
    for (int j = 0; j < 4; ++j) {
        float4 v = *(const float4*)(row + j * 4);
        sq[(j * 4 + 0) & 7] += v.x * v.x;
        sq[(j * 4 + 1) & 7] += v.y * v.y;
        sq[(j * 4 + 2) & 7] += v.z * v.z;
        sq[(j * 4 + 3) & 7] += v.w * v.w;
    }
#pragma unroll
    for (int k = 0; k < 8; ++k) {
        float v = sq[k];
        v += __shfl_xor(v, 1);  v += __shfl_xor(v, 2);  v += __shfl_xor(v, 4);
        v += __shfl_xor(v, 8);  v += __shfl_xor(v, 16); v += __shfl_xor(v, 32);
        sq[k] = v;
    }
    int lane = t & 63, wv = t >> 6;
    if (lane == 0) {
#pragma unroll
        for (int k = 0; k < 8; ++k) red[wv][k] = sq[k];
    }
    __syncthreads();
    if (t < 8) {
        float s = red[0][t] + red[1][t] + red[2][t] + red[3][t];
        inv_norm[b * 8 + t] = 1.0f / sqrtf(s);
    }
}

// ---------------------------------------------------------------------------
// 6) edge kernel: wave handles 8 edges of one batch; q row in 64 VGPRs.
//    node_h is bf16 now -> gather traffic halved (16B/lane per row).
__global__ __launch_bounds__(256) void edge_k(const int* __restrict__ idxs,
                                              const unsigned short* __restrict__ node_h,
                                              const float* __restrict__ q_h,
                                              const float* __restrict__ inv_norm,
                                              float* __restrict__ out) {
    int t = threadIdx.x;
    int lane = t & 63;
    int gw = blockIdx.x * 4 + (t >> 6);   // 0..4095
    int m0 = gw * 8;
    int b = m0 >> 9;                       // edges sorted by batch: m//E

    // lane l holds q_h[b][l*64 .. l*64+63]  (h = l*8+i, k = 0..7)
    const float* qrow = q_h + (size_t)b * 4096 + lane * 64;
    float q[64];
#pragma unroll
    for (int i = 0; i < 16; ++i) {
        float4 v = *(const float4*)(qrow + i * 4);
        q[i * 4 + 0] = v.x; q[i * 4 + 1] = v.y; q[i * 4 + 2] = v.z; q[i * 4 + 3] = v.w;
    }
    float4 inv0 = *(const float4*)(inv_norm + b * 8);
    float4 inv1 = *(const float4*)(inv_norm + b * 8 + 4);
    const unsigned short* nb = node_h + (size_t)b * 64 * 512;

#pragma unroll 2
    for (int e = 0; e < 8; ++e) {
        int m = m0 + e;
        int idx = idxs[m];
        int r = idx & 4095;
        int src = r >> 6, dst = r & 63;
        union { uint4 u4; unsigned short us[8]; } S, D;
        S.u4 = *(const uint4*)(nb + (size_t)src * 512 + lane * 8);
        D.u4 = *(const uint4*)(nb + (size_t)dst * 512 + lane * 8);
        float obj[8];
#pragma unroll
        for (int i = 0; i < 8; ++i) obj[i] = bf2f(S.us[i]) + bf2f(D.us[i]);
        float acc[8] = {0.f, 0.f, 0.f, 0.f, 0.f, 0.f, 0.f, 0.f};
#pragma unroll
        for (int i = 0; i < 8; ++i)
#pragma unroll
            for (int k = 0; k < 8; ++k)
                acc[k] = fmaf(obj[i], q[i * 8 + k], acc[k]);
#pragma unroll
        for (int k = 0; k < 8; ++k) {
            float v = acc[k];
            v += __shfl_xor(v, 1);  v += __shfl_xor(v, 2);  v += __shfl_xor(v, 4);
            v += __shfl_xor(v, 8);  v += __shfl_xor(v, 16); v += __shfl_xor(v, 32);
            acc[k] = v;
        }
        if (lane == 0) {
            float4 o0 = {acc[0] * inv0.x, acc[1] * inv0.y, acc[2] * inv0.z, acc[3] * inv0.w};
            float4 o1 = {acc[4] * inv1.x, acc[5] * inv1.y, acc[6] * inv1.z, acc[7] * inv1.w};
            *(float4*)(out + (size_t)m * 8) = o0;
            *(float4*)(out + (size_t)m * 8 + 4) = o1;
        }
    }
}

// ---------------------------------------------------------------------------
extern "C" void kernel_launch(void* const* d_in, const int* in_sizes, int n_in,
                              void* d_out, int out_size, void* d_ws, size_t ws_size,
                              hipStream_t stream) {
    const float* node_feats = (const float*)d_in[0];  // [64][64][2048]
    const float* q_feats    = (const float*)d_in[1];  // [64][1024]
    const int*   indexes    = (const int*)d_in[2];    // [32768]
    const float* W_obj      = (const float*)d_in[3];  // [2048][512]
    const float* b_obj      = (const float*)d_in[4];  // [512]
    const float* W_q        = (const float*)d_in[5];  // [1024][4096]
    const float* b_q        = (const float*)d_in[6];  // [4096]
    float* out = (float*)d_out;                       // [32768][8]

    char* ws = (char*)d_ws;
    unsigned short* W_T    = (unsigned short*)(ws + 0);        // 2.10MB
    unsigned short* node_h = (unsigned short*)(ws + 2097152);  // 4.19MB bf16
    float* part            = (float*)(ws + 6291456);           // 8.39MB
    float* q_h             = (float*)(ws + 14680064);          // 1.05MB
    float* inv_norm        = (float*)(ws + 15728640);          // 2KB

    cvt_bt<<<dim3(64, 16), 256, 0, stream>>>(W_obj, W_T);
    gemm1<<<512, 256, 0, stream>>>(node_feats, W_T, b_obj, node_h);
    gemm2<<<dim3(32, 8), 256, 0, stream>>>(q_feats, W_q, part);
    finish_q<<<256, 256, 0, stream>>>(part, b_q, q_h);
    norms_k<<<64, 256, 0, stream>>>(q_h, inv_norm);
    edge_k<<<1024, 256, 0, stream>>>(indexes, node_h, q_h, inv_norm, out);
}

// Round 6
// 92.115 us; speedup vs baseline: 1.2997x; 1.2997x over previous
//
#include <hip/hip_runtime.h>
#include <hip/hip_bf16.h>

// Problem constants (EdgeQProj): B=64, N=64, E=512, OBJ_DIM=2048, Q_DIM=1024,
// HID=512, KS=8. M_edges = B*E = 32768.

using bf16x8 = __attribute__((ext_vector_type(8))) __bf16;
using f32x4  = __attribute__((ext_vector_type(4))) float;

__device__ __forceinline__ unsigned short f2bf(float f) {
    unsigned int u = __float_as_uint(f);
    unsigned int r = (u + 0x7FFFu + ((u >> 16) & 1u)) >> 16;  // RNE
    return (unsigned short)r;
}

// async global->LDS, 16B per lane: LDS dest = wave-uniform base + lane*16,
// global src = per-lane address. Completion tracked by vmcnt; __syncthreads()
// drains vmcnt(0) before s_barrier, which is the only sync we rely on.
__device__ __forceinline__ void gl_lds16(const void* g, void* l) {
    __builtin_amdgcn_global_load_lds(
        (const __attribute__((address_space(1))) unsigned int*)g,
        (__attribute__((address_space(3))) unsigned int*)l,
        16, 0, 0);
}

// ---------------------------------------------------------------------------
// 1) node_feats fp32 [4096][2048] -> bf16 (workspace), one pass
__global__ __launch_bounds__(256) void cvt_a(const float* __restrict__ in,
                                             unsigned short* __restrict__ out) {
    int tid = blockIdx.x * 256 + threadIdx.x;          // 2048*256 = 524288
    for (int p = tid; p < 2097152; p += 524288) {      // 8388608/4 float4s
        float4 v = *(const float4*)(in + (size_t)p * 4);
        ushort4 o;
        o.x = f2bf(v.x); o.y = f2bf(v.y); o.z = f2bf(v.z); o.w = f2bf(v.w);
        *(ushort4*)(out + (size_t)p * 4) = o;
    }
}

// ---------------------------------------------------------------------------
// 2) W_obj fp32 [2048][512] -> W_T bf16 [512][2048]  (tiled transpose)
__global__ __launch_bounds__(256) void cvt_bt(const float* __restrict__ W,
                                              unsigned short* __restrict__ WT) {
    __shared__ float lds[32][33];
    int k0 = blockIdx.x * 32, n0 = blockIdx.y * 32;
    int tx = threadIdx.x & 31, ty = threadIdx.x >> 5;  // ty 0..7
#pragma unroll
    for (int j = 0; j < 4; ++j)
        lds[ty + j * 8][tx] = W[(size_t)(k0 + ty + j * 8) * 512 + n0 + tx];
    __syncthreads();
#pragma unroll
    for (int j = 0; j < 4; ++j)
        WT[(size_t)(n0 + ty + j * 8) * 2048 + k0 + tx] = f2bf(lds[tx][ty + j * 8]);
}

// ---------------------------------------------------------------------------
// 3) GEMM1 (m97-structure): node_h[4096][512] = relu(A@B^T + b), A,B bf16.
//    BM=128 BN=64 BK=64, 512 thr (8 waves 4x2), LINEAR LDS (global_load_lds
//    requires linear dest), 3 async wave-loads + 8 MFMAs per k-step,
//    2-barrier loop. fp32 C (coalesced stores). XCD swizzle: per-XCD slice
//    = 4 m-panels A (2MB bf16) + full B (2MB) = 4MB -> L2-resident.
__global__ __launch_bounds__(512) void gemm1(const unsigned short* __restrict__ A,
                                             const unsigned short* __restrict__ BT,
                                             const float* __restrict__ bias,
                                             float* __restrict__ C) {
    __shared__ __align__(16) unsigned short Asm[128 * 64];
    __shared__ __align__(16) unsigned short Bsm[64 * 64];

    int bid = blockIdx.x;
    int swz = (bid & 7) * 32 + (bid >> 3);
    int by = swz >> 3, bx = swz & 7;
    int m0 = by * 128, n0 = bx * 64;

    int t = threadIdx.x;
    int lane = t & 63, w = t >> 6;
    int wm = w >> 1, wn = w & 1;              // wave grid 4x2
    int l15 = lane & 15, l16 = lane >> 4;

    // staging geometry: 1KB chunk = 8 rows x 64 cols bf16; lane covers
    // (row = lane/8, colchunk = lane%8) within its wave's chunk.
    int lrow = lane >> 3, lcol = (lane & 7) * 8;
    const unsigned short* gaB = A  + (size_t)(m0 + w * 16 + lrow) * 2048 + lcol;
    const unsigned short* gbB = BT + (size_t)(n0 + w * 8  + lrow) * 2048 + lcol;
    unsigned short* la0 = Asm + w * 1024;        // rows w*16   .. w*16+8
    unsigned short* la1 = Asm + w * 1024 + 512;  // rows w*16+8 .. w*16+16
    unsigned short* lb  = Bsm + w * 512;         // rows w*8    .. w*8+8

    f32x4 acc[2][2];
#pragma unroll
    for (int i = 0; i < 2; ++i)
#pragma unroll
        for (int j = 0; j < 2; ++j) acc[i][j] = (f32x4){0.f, 0.f, 0.f, 0.f};

    for (int k0 = 0; k0 < 2048; k0 += 64) {
        // ---- async stage (issued after previous step's trailing barrier) --
        gl_lds16(gaB + k0, la0);
        gl_lds16(gaB + k0 + (size_t)8 * 2048, la1);
        gl_lds16(gbB + k0, lb);
        __syncthreads();                       // vmcnt(0) drain + barrier

        // ---- compute: 2 ksubs x (2x2) MFMAs ----
#pragma unroll
        for (int s = 0; s < 2; ++s) {
            const unsigned short* ab = Asm + (size_t)(wm * 32) * 64 + s * 32 + l16 * 8;
            const unsigned short* bb = Bsm + (size_t)(wn * 32) * 64 + s * 32 + l16 * 8;
            bf16x8 a0 = *(const bf16x8*)(ab + (size_t)l15 * 64);
            bf16x8 a1 = *(const bf16x8*)(ab + (size_t)(16 + l15) * 64);
            bf16x8 b0 = *(const bf16x8*)(bb + (size_t)l15 * 64);
            bf16x8 b1 = *(const bf16x8*)(bb + (size_t)(16 + l15) * 64);
            acc[0][0] = __builtin_amdgcn_mfma_f32_16x16x32_bf16(a0, b0, acc[0][0], 0, 0, 0);
            acc[0][1] = __builtin_amdgcn_mfma_f32_16x16x32_bf16(a0, b1, acc[0][1], 0, 0, 0);
            acc[1][0] = __builtin_amdgcn_mfma_f32_16x16x32_bf16(a1, b0, acc[1][0], 0, 0, 0);
            acc[1][1] = __builtin_amdgcn_mfma_f32_16x16x32_bf16(a1, b1, acc[1][1], 0, 0, 0);
        }
        __syncthreads();                       // readers done before re-stage
    }

    // ---- epilogue: bias + relu -> fp32; D: col=lane&15, row=(lane>>4)*4+j --
#pragma unroll
    for (int fm = 0; fm < 2; ++fm)
#pragma unroll
        for (int fn = 0; fn < 2; ++fn) {
            int col = n0 + wn * 32 + fn * 16 + l15;
            float bv = bias[col];
#pragma unroll
            for (int j = 0; j < 4; ++j) {
                int row = m0 + wm * 32 + fm * 16 + l16 * 4 + j;
                float v = acc[fm][fn][j] + bv;
                C[(size_t)row * 512 + col] = v > 0.f ? v : 0.f;
            }
        }
}

// ---------------------------------------------------------------------------
// 4) GEMM2 (fused fp32->bf16 MFMA, single-pass W_q):
//    part[z][64][4096] = q[64][k0:k0+128] @ W_q[k0:k0+128][c0:c0+128]
//    grid (32 colblocks, 8 ksplits) = 256 blocks x 256 thr (4 waves).
#define LDK2 136
__global__ __launch_bounds__(256) void gemm2(const float* __restrict__ qf,
                                             const float* __restrict__ Wq,
                                             float* __restrict__ part) {
    __shared__ __align__(16) unsigned short Asm[64][LDK2];   // q tile  [m][k]
    __shared__ __align__(16) unsigned short Bsm[128][LDK2];  // W tile  [c][k]

    int t = threadIdx.x;
    int lane = t & 63, w = t >> 6;          // 4 waves, wave owns 32 cols
    int l15 = lane & 15, l16 = lane >> 4;
    int c0 = blockIdx.x * 128;
    int k0 = blockIdx.y * 128;

    // ---- stage A: q[64][k0:k0+128] fp32 -> bf16 ----
#pragma unroll
    for (int j = 0; j < 4; ++j) {
        int g = t + j * 256;                 // 1024 chunks of 8k
        int row = g >> 4, kc = g & 15;
        const float* src = qf + (size_t)row * 1024 + k0 + kc * 8;
        float4 v0 = *(const float4*)(src);
        float4 v1 = *(const float4*)(src + 4);
        union { unsigned short us[8]; uint4 u4; } p;
        p.us[0] = f2bf(v0.x); p.us[1] = f2bf(v0.y); p.us[2] = f2bf(v0.z); p.us[3] = f2bf(v0.w);
        p.us[4] = f2bf(v1.x); p.us[5] = f2bf(v1.y); p.us[6] = f2bf(v1.z); p.us[7] = f2bf(v1.w);
        *(uint4*)(&Asm[row][kc * 8]) = p.u4;
    }
    // ---- stage B: W_q[k0:k0+128][c0:c0+128] fp32 -> bf16, transposed ----
#pragma unroll
    for (int j = 0; j < 2; ++j) {
        int g = t + j * 256;                 // 512 units of 8k x 4c
        int kg = g >> 5, cg = g & 31;
        f32x4 wv[8];
#pragma unroll
        for (int kk = 0; kk < 8; ++kk)
            wv[kk] = *(const f32x4*)(Wq + (size_t)(k0 + kg * 8 + kk) * 4096 + c0 + cg * 4);
#pragma unroll
        for (int cc = 0; cc < 4; ++cc) {
            union { unsigned short us[8]; uint4 u4; } p;
#pragma unroll
            for (int kk = 0; kk < 8; ++kk) p.us[kk] = f2bf(wv[kk][cc]);
            *(uint4*)(&Bsm[cg * 4 + cc][kg * 8]) = p.u4;
        }
    }
    __syncthreads();

    // ---- MFMA: wave w covers cols [w*32, w*32+32); 4m x 2n x 4k frags ----
    f32x4 acc[4][2];
#pragma unroll
    for (int i = 0; i < 4; ++i)
#pragma unroll
        for (int j = 0; j < 2; ++j) acc[i][j] = (f32x4){0.f, 0.f, 0.f, 0.f};

#pragma unroll
    for (int ks = 0; ks < 4; ++ks) {
        bf16x8 bfr[2];
#pragma unroll
        for (int jn = 0; jn < 2; ++jn)
            bfr[jn] = *(const bf16x8*)(&Bsm[w * 32 + jn * 16 + l15][ks * 32 + l16 * 8]);
#pragma unroll
        for (int i = 0; i < 4; ++i) {
            bf16x8 afr = *(const bf16x8*)(&Asm[i * 16 + l15][ks * 32 + l16 * 8]);
            acc[i][0] = __builtin_amdgcn_mfma_f32_16x16x32_bf16(afr, bfr[0], acc[i][0], 0, 0, 0);
            acc[i][1] = __builtin_amdgcn_mfma_f32_16x16x32_bf16(afr, bfr[1], acc[i][1], 0, 0, 0);
        }
    }

    // ---- write partials ----
    float* pz = part + (size_t)blockIdx.y * 262144;
#pragma unroll
    for (int i = 0; i < 4; ++i)
#pragma unroll
        for (int jn = 0; jn < 2; ++jn) {
            int col = c0 + w * 32 + jn * 16 + l15;
#pragma unroll
            for (int j = 0; j < 4; ++j) {
                int row = i * 16 + l16 * 4 + j;
                pz[(size_t)row * 4096 + col] = acc[i][jn][j];
            }
        }
}

// 5) reduce partials + bias + relu -> q_h[64][4096]
__global__ __launch_bounds__(256) void finish_q(const float* __restrict__ part,
                                                const float* __restrict__ bq,
                                                float* __restrict__ q_h) {
    int base = (blockIdx.x * 256 + threadIdx.x) * 4;
    f32x4 a = (f32x4){0.f, 0.f, 0.f, 0.f};
#pragma unroll
    for (int s = 0; s < 8; ++s) a += *(const f32x4*)(part + (size_t)s * 262144 + base);
    f32x4 bb = *(const f32x4*)(bq + (base & 4095));
#pragma unroll
    for (int j = 0; j < 4; ++j) {
        float v = a[j] + bb[j];
        a[j] = v > 0.f ? v : 0.f;
    }
    *(f32x4*)(q_h + base) = a;
}

// 6) inv_norm[b][k] = 1/sqrt(sum_h q_h[b][h*8+k]^2)
__global__ __launch_bounds__(256) void norms_k(const float* __restrict__ q_h,
                                               float* __restrict__ inv_norm) {
    __shared__ float red[4][8];
    int b = blockIdx.x, t = threadIdx.x;
    const float* row = q_h + (size_t)b * 4096 + t * 16;
    float sq[8] = {0.f, 0.f, 0.f, 0.f, 0.f, 0.f, 0.f, 0.f};
#pragma unroll
    for (int j = 0; j < 4; ++j) {
        float4 v = *(const float4*)(row + j * 4);
        sq[(j * 4 + 0) & 7] += v.x * v.x;
        sq[(j * 4 + 1) & 7] += v.y * v.y;
        sq[(j * 4 + 2) & 7] += v.z * v.z;
        sq[(j * 4 + 3) & 7] += v.w * v.w;
    }
#pragma unroll
    for (int k = 0; k < 8; ++k) {
        float v = sq[k];
        v += __shfl_xor(v, 1);  v += __shfl_xor(v, 2);  v += __shfl_xor(v, 4);
        v += __shfl_xor(v, 8);  v += __shfl_xor(v, 16); v += __shfl_xor(v, 32);
        sq[k] = v;
    }
    int lane = t & 63, wv = t >> 6;
    if (lane == 0) {
#pragma unroll
        for (int k = 0; k < 8; ++k) red[wv][k] = sq[k];
    }
    __syncthreads();
    if (t < 8) {
        float s = red[0][t] + red[1][t] + red[2][t] + red[3][t];
        inv_norm[b * 8 + t] = 1.0f / sqrtf(s);
    }
}

// ---------------------------------------------------------------------------
// 7) edge kernel: wave handles 8 edges of one batch; q row lives in 64 VGPRs.
__global__ __launch_bounds__(256) void edge_k(const int* __restrict__ idxs,
                                              const float* __restrict__ node_h,
                                              const float* __restrict__ q_h,
                                              const float* __restrict__ inv_norm,
                                              float* __restrict__ out) {
    int t = threadIdx.x;
    int lane = t & 63;
    int gw = blockIdx.x * 4 + (t >> 6);   // 0..4095
    int m0 = gw * 8;
    int b = m0 >> 9;                       // edges sorted by batch: m//E

    // lane l holds q_h[b][l*64 .. l*64+63]  (h = l*8+i, k = 0..7)
    const float* qrow = q_h + (size_t)b * 4096 + lane * 64;
    float q[64];
#pragma unroll
    for (int i = 0; i < 16; ++i) {
        float4 v = *(const float4*)(qrow + i * 4);
        q[i * 4 + 0] = v.x; q[i * 4 + 1] = v.y; q[i * 4 + 2] = v.z; q[i * 4 + 3] = v.w;
    }
    float4 inv0 = *(const float4*)(inv_norm + b * 8);
    float4 inv1 = *(const float4*)(inv_norm + b * 8 + 4);
    const float* nb = node_h + (size_t)b * 64 * 512;

#pragma unroll 2
    for (int e = 0; e < 8; ++e) {
        int m = m0 + e;
        int idx = idxs[m];
        int r = idx & 4095;
        int src = r >> 6, dst = r & 63;
        const float* sp = nb + (size_t)src * 512 + lane * 8;
        const float* dp = nb + (size_t)dst * 512 + lane * 8;
        float4 s0 = *(const float4*)(sp), s1 = *(const float4*)(sp + 4);
        float4 d0 = *(const float4*)(dp), d1 = *(const float4*)(dp + 4);
        float obj[8] = {s0.x + d0.x, s0.y + d0.y, s0.z + d0.z, s0.w + d0.w,
                        s1.x + d1.x, s1.y + d1.y, s1.z + d1.z, s1.w + d1.w};
        float acc[8] = {0.f, 0.f, 0.f, 0.f, 0.f, 0.f, 0.f, 0.f};
#pragma unroll
        for (int i = 0; i < 8; ++i)
#pragma unroll
            for (int k = 0; k < 8; ++k)
                acc[k] = fmaf(obj[i], q[i * 8 + k], acc[k]);
#pragma unroll
        for (int k = 0; k < 8; ++k) {
            float v = acc[k];
            v += __shfl_xor(v, 1);  v += __shfl_xor(v, 2);  v += __shfl_xor(v, 4);
            v += __shfl_xor(v, 8);  v += __shfl_xor(v, 16); v += __shfl_xor(v, 32);
            acc[k] = v;
        }
        if (lane == 0) {
            float4 o0 = {acc[0] * inv0.x, acc[1] * inv0.y, acc[2] * inv0.z, acc[3] * inv0.w};
            float4 o1 = {acc[4] * inv1.x, acc[5] * inv1.y, acc[6] * inv1.z, acc[7] * inv1.w};
            *(float4*)(out + (size_t)m * 8) = o0;
            *(float4*)(out + (size_t)m * 8 + 4) = o1;
        }
    }
}

// ---------------------------------------------------------------------------
extern "C" void kernel_launch(void* const* d_in, const int* in_sizes, int n_in,
                              void* d_out, int out_size, void* d_ws, size_t ws_size,
                              hipStream_t stream) {
    const float* node_feats = (const float*)d_in[0];  // [64][64][2048]
    const float* q_feats    = (const float*)d_in[1];  // [64][1024]
    const int*   indexes    = (const int*)d_in[2];    // [32768]
    const float* W_obj      = (const float*)d_in[3];  // [2048][512]
    const float* b_obj      = (const float*)d_in[4];  // [512]
    const float* W_q        = (const float*)d_in[5];  // [1024][4096]
    const float* b_q        = (const float*)d_in[6];  // [4096]
    float* out = (float*)d_out;                       // [32768][8]

    char* ws = (char*)d_ws;
    // A bf16 region (16.78MB) is reused as gemm2 partials (8.39MB) after gemm1.
    unsigned short* A_bf16 = (unsigned short*)(ws + 0);
    unsigned short* W_T    = (unsigned short*)(ws + 16777216);  // 2.10MB
    float* node_h          = (float*)(ws + 18874368);           // 8.39MB
    float* q_h             = (float*)(ws + 27262976);           // 1.05MB
    float* inv_norm        = (float*)(ws + 28311552);           // 2KB
    float* part            = (float*)(ws + 0);                  // aliases A_bf16

    cvt_a<<<2048, 256, 0, stream>>>(node_feats, A_bf16);
    cvt_bt<<<dim3(64, 16), 256, 0, stream>>>(W_obj, W_T);
    gemm1<<<256, 512, 0, stream>>>(A_bf16, W_T, b_obj, node_h);
    gemm2<<<dim3(32, 8), 256, 0, stream>>>(q_feats, W_q, part);   // after gemm1 (aliasing)
    finish_q<<<256, 256, 0, stream>>>(part, b_q, q_h);
    norms_k<<<64, 256, 0, stream>>>(q_h, inv_norm);
    edge_k<<<1024, 256, 0, stream>>>(indexes, node_h, q_h, inv_norm, out);
}

// Round 7
// 67.226 us; speedup vs baseline: 1.7809x; 1.3702x over previous
//
#include <hip/hip_runtime.h>
#include <hip/hip_bf16.h>

// Problem constants (EdgeQProj): B=64, N=64, E=512, OBJ_DIM=2048, Q_DIM=1024,
// HID=512, KS=8. M_edges = B*E = 32768.
//
// Pipeline (key identity: edge_logit[m] = P[b,src]+P[b,dst],
//           P[b] = relu(node_feats@W_obj+b) @ q_e[b] * inv_norm[b]):
//   cvt_a    : node_feats fp32 -> bf16 (one pass)
//   cvt_bt   : W_obj -> W_T bf16 transposed
//   gemm1    : node_h = relu(A@W^T + b)  (bf16 MFMA, fp32 out)
//   gemm2    : q partials (fused fp32->bf16 MFMA, single-pass W_q)
//   finish_q : reduce + bias + relu -> q_h fp32
//   norms_k  : inv_norm[b][k]
//   p_k      : P[b][n][k] = (node_h[b] @ q_e[b]) * inv_norm[b][k]  (MFMA)
//   edge2    : out[m] = P[b][src] + P[b][dst]   (trivial gather-add)

using bf16x8 = __attribute__((ext_vector_type(8))) __bf16;
using f32x4  = __attribute__((ext_vector_type(4))) float;

__device__ __forceinline__ unsigned short f2bf(float f) {
    unsigned int u = __float_as_uint(f);
    unsigned int r = (u + 0x7FFFu + ((u >> 16) & 1u)) >> 16;  // RNE
    return (unsigned short)r;
}

__device__ __forceinline__ bf16x8 pk8(f32x4 a, f32x4 b) {
    union { unsigned short us[8]; bf16x8 v; } r;
    r.us[0] = f2bf(a[0]); r.us[1] = f2bf(a[1]); r.us[2] = f2bf(a[2]); r.us[3] = f2bf(a[3]);
    r.us[4] = f2bf(b[0]); r.us[5] = f2bf(b[1]); r.us[6] = f2bf(b[2]); r.us[7] = f2bf(b[3]);
    return r.v;
}

// ---------------------------------------------------------------------------
// 1) node_feats fp32 [4096][2048] -> bf16 (workspace), one pass
__global__ __launch_bounds__(256) void cvt_a(const float* __restrict__ in,
                                             unsigned short* __restrict__ out) {
    int tid = blockIdx.x * 256 + threadIdx.x;          // 2048*256 = 524288
    for (int p = tid; p < 2097152; p += 524288) {      // 8388608/4 float4s
        float4 v = *(const float4*)(in + (size_t)p * 4);
        ushort4 o;
        o.x = f2bf(v.x); o.y = f2bf(v.y); o.z = f2bf(v.z); o.w = f2bf(v.w);
        *(ushort4*)(out + (size_t)p * 4) = o;
    }
}

// ---------------------------------------------------------------------------
// 2) W_obj fp32 [2048][512] -> W_T bf16 [512][2048]  (tiled transpose)
__global__ __launch_bounds__(256) void cvt_bt(const float* __restrict__ W,
                                              unsigned short* __restrict__ WT) {
    __shared__ float lds[32][33];
    int k0 = blockIdx.x * 32, n0 = blockIdx.y * 32;
    int tx = threadIdx.x & 31, ty = threadIdx.x >> 5;  // ty 0..7
#pragma unroll
    for (int j = 0; j < 4; ++j)
        lds[ty + j * 8][tx] = W[(size_t)(k0 + ty + j * 8) * 512 + n0 + tx];
    __syncthreads();
#pragma unroll
    for (int j = 0; j < 4; ++j)
        WT[(size_t)(n0 + ty + j * 8) * 2048 + k0 + tx] = f2bf(lds[tx][ty + j * 8]);
}

// ---------------------------------------------------------------------------
// 3) GEMM1 (R2 structure + register prefetch): node_h[4096][512](fp32)
//    = relu(A_bf16 @ W_T^T + b). BM=128 BN=64 BK=64, 512 thr (8 waves 4x2),
//    LDK=40 padded LDS (2-way bank aliasing, free). Next k-step's global
//    loads issue between the barrier and this step's MFMAs.
#define LDK 40
__global__ __launch_bounds__(512) void gemm1(const unsigned short* __restrict__ A,
                                             const unsigned short* __restrict__ BT,
                                             const float* __restrict__ bias,
                                             float* __restrict__ C) {
    __shared__ __align__(16) unsigned short Asm[2][128][LDK];
    __shared__ __align__(16) unsigned short Bsm[2][64][LDK];

    // XCD swizzle: grid 256 (%8==0, bijective). per-XCD: 4 A m-panels
    // (2.1MB bf16) + full B (2MB) ~ L2-resident.
    int bid = blockIdx.x;
    int swz = (bid & 7) * 32 + (bid >> 3);
    int by = swz >> 3, bx = swz & 7;
    int m0 = by * 128, n0 = bx * 64;

    int t = threadIdx.x;
    int lane = t & 63, w = t >> 6;
    int wm = w >> 1, wn = w & 1;              // wave grid 4x2
    int l15 = lane & 15, l16 = lane >> 4;

    int ar0 = t >> 3, akc = t & 7;            // staging row / k-chunk
    const unsigned short* aB = A  + (size_t)(m0 + ar0) * 2048 + akc * 8;
    const unsigned short* bB = BT + (size_t)(n0 + ar0) * 2048 + akc * 8;

    uint4 ra0 = *(const uint4*)(aB);
    uint4 ra1 = *(const uint4*)(aB + (size_t)64 * 2048);
    uint4 rb  = *(const uint4*)(bB);

    f32x4 acc[2][2];
#pragma unroll
    for (int i = 0; i < 2; ++i)
#pragma unroll
        for (int j = 0; j < 2; ++j) acc[i][j] = (f32x4){0.f, 0.f, 0.f, 0.f};

    for (int s = 0; s < 32; ++s) {
        // LDS write of prefetched tile (vmcnt wait lands here)
        *(uint4*)(&Asm[akc >> 2][ar0][(akc & 3) * 8])      = ra0;
        *(uint4*)(&Asm[akc >> 2][ar0 + 64][(akc & 3) * 8]) = ra1;
        *(uint4*)(&Bsm[akc >> 2][ar0][(akc & 3) * 8])      = rb;
        __syncthreads();

        // issue next step's loads; awaited only at next LDS write
        if (s < 31) {
            int ko = (s + 1) * 64;
            ra0 = *(const uint4*)(aB + ko);
            ra1 = *(const uint4*)(aB + (size_t)64 * 2048 + ko);
            rb  = *(const uint4*)(bB + ko);
        }

        // compute: 2 ksubs x (2x2) MFMAs
#pragma unroll
        for (int ss = 0; ss < 2; ++ss) {
            bf16x8 a0 = *(const bf16x8*)(&Asm[ss][wm * 32 + l15][l16 * 8]);
            bf16x8 a1 = *(const bf16x8*)(&Asm[ss][wm * 32 + 16 + l15][l16 * 8]);
            bf16x8 b0 = *(const bf16x8*)(&Bsm[ss][wn * 32 + l15][l16 * 8]);
            bf16x8 b1 = *(const bf16x8*)(&Bsm[ss][wn * 32 + 16 + l15][l16 * 8]);
            acc[0][0] = __builtin_amdgcn_mfma_f32_16x16x32_bf16(a0, b0, acc[0][0], 0, 0, 0);
            acc[0][1] = __builtin_amdgcn_mfma_f32_16x16x32_bf16(a0, b1, acc[0][1], 0, 0, 0);
            acc[1][0] = __builtin_amdgcn_mfma_f32_16x16x32_bf16(a1, b0, acc[1][0], 0, 0, 0);
            acc[1][1] = __builtin_amdgcn_mfma_f32_16x16x32_bf16(a1, b1, acc[1][1], 0, 0, 0);
        }
        __syncthreads();
    }

    // epilogue: bias + relu -> fp32; D layout col=lane&15, row=(lane>>4)*4+j
#pragma unroll
    for (int fm = 0; fm < 2; ++fm)
#pragma unroll
        for (int fn = 0; fn < 2; ++fn) {
            int col = n0 + wn * 32 + fn * 16 + l15;
            float bv = bias[col];
#pragma unroll
            for (int j = 0; j < 4; ++j) {
                int row = m0 + wm * 32 + fm * 16 + l16 * 4 + j;
                float v = acc[fm][fn][j] + bv;
                C[(size_t)row * 512 + col] = v > 0.f ? v : 0.f;
            }
        }
}

// ---------------------------------------------------------------------------
// 4) GEMM2 (fused fp32->bf16 MFMA, single-pass W_q):
//    part[z][64][4096] = q[64][k0:k0+128] @ W_q[k0:k0+128][c0:c0+128]
//    grid (32 colblocks, 8 ksplits) = 256 blocks x 256 thr (4 waves).
#define LDK2 136
__global__ __launch_bounds__(256) void gemm2(const float* __restrict__ qf,
                                             const float* __restrict__ Wq,
                                             float* __restrict__ part) {
    __shared__ __align__(16) unsigned short Asm[64][LDK2];   // q tile  [m][k]
    __shared__ __align__(16) unsigned short Bsm[128][LDK2];  // W tile  [c][k]

    int t = threadIdx.x;
    int lane = t & 63, w = t >> 6;          // 4 waves, wave owns 32 cols
    int l15 = lane & 15, l16 = lane >> 4;
    int c0 = blockIdx.x * 128;
    int k0 = blockIdx.y * 128;

    // ---- stage A: q[64][k0:k0+128] fp32 -> bf16 ----
#pragma unroll
    for (int j = 0; j < 4; ++j) {
        int g = t + j * 256;                 // 1024 chunks of 8k
        int row = g >> 4, kc = g & 15;
        const float* src = qf + (size_t)row * 1024 + k0 + kc * 8;
        f32x4 v0 = *(const f32x4*)(src);
        f32x4 v1 = *(const f32x4*)(src + 4);
        *(bf16x8*)(&Asm[row][kc * 8]) = pk8(v0, v1);
    }
    // ---- stage B: W_q[k0:k0+128][c0:c0+128] fp32 -> bf16, transposed ----
#pragma unroll
    for (int j = 0; j < 2; ++j) {
        int g = t + j * 256;                 // 512 units of 8k x 4c
        int kg = g >> 5, cg = g & 31;
        f32x4 wv[8];
#pragma unroll
        for (int kk = 0; kk < 8; ++kk)
            wv[kk] = *(const f32x4*)(Wq + (size_t)(k0 + kg * 8 + kk) * 4096 + c0 + cg * 4);
#pragma unroll
        for (int cc = 0; cc < 4; ++cc) {
            union { unsigned short us[8]; uint4 u4; } p;
#pragma unroll
            for (int kk = 0; kk < 8; ++kk) p.us[kk] = f2bf(wv[kk][cc]);
            *(uint4*)(&Bsm[cg * 4 + cc][kg * 8]) = p.u4;
        }
    }
    __syncthreads();

    // ---- MFMA: wave w covers cols [w*32, w*32+32); 4m x 2n x 4k frags ----
    f32x4 acc[4][2];
#pragma unroll
    for (int i = 0; i < 4; ++i)
#pragma unroll
        for (int j = 0; j < 2; ++j) acc[i][j] = (f32x4){0.f, 0.f, 0.f, 0.f};

#pragma unroll
    for (int ks = 0; ks < 4; ++ks) {
        bf16x8 bfr[2];
#pragma unroll
        for (int jn = 0; jn < 2; ++jn)
            bfr[jn] = *(const bf16x8*)(&Bsm[w * 32 + jn * 16 + l15][ks * 32 + l16 * 8]);
#pragma unroll
        for (int i = 0; i < 4; ++i) {
            bf16x8 afr = *(const bf16x8*)(&Asm[i * 16 + l15][ks * 32 + l16 * 8]);
            acc[i][0] = __builtin_amdgcn_mfma_f32_16x16x32_bf16(afr, bfr[0], acc[i][0], 0, 0, 0);
            acc[i][1] = __builtin_amdgcn_mfma_f32_16x16x32_bf16(afr, bfr[1], acc[i][1], 0, 0, 0);
        }
    }

    // ---- write partials ----
    float* pz = part + (size_t)blockIdx.y * 262144;
#pragma unroll
    for (int i = 0; i < 4; ++i)
#pragma unroll
        for (int jn = 0; jn < 2; ++jn) {
            int col = c0 + w * 32 + jn * 16 + l15;
#pragma unroll
            for (int j = 0; j < 4; ++j) {
                int row = i * 16 + l16 * 4 + j;
                pz[(size_t)row * 4096 + col] = acc[i][jn][j];
            }
        }
}

// 5) reduce partials + bias + relu -> q_h[64][4096]
__global__ __launch_bounds__(256) void finish_q(const float* __restrict__ part,
                                                const float* __restrict__ bq,
                                                float* __restrict__ q_h) {
    int base = (blockIdx.x * 256 + threadIdx.x) * 4;
    f32x4 a = (f32x4){0.f, 0.f, 0.f, 0.f};
#pragma unroll
    for (int s = 0; s < 8; ++s) a += *(const f32x4*)(part + (size_t)s * 262144 + base);
    f32x4 bb = *(const f32x4*)(bq + (base & 4095));
#pragma unroll
    for (int j = 0; j < 4; ++j) {
        float v = a[j] + bb[j];
        a[j] = v > 0.f ? v : 0.f;
    }
    *(f32x4*)(q_h + base) = a;
}

// 6) inv_norm[b][k] = 1/sqrt(sum_h q_h[b][h*8+k]^2)
__global__ __launch_bounds__(256) void norms_k(const float* __restrict__ q_h,
                                               float* __restrict__ inv_norm) {
    __shared__ float red[4][8];
    int b = blockIdx.x, t = threadIdx.x;
    const float* row = q_h + (size_t)b * 4096 + t * 16;
    float sq[8] = {0.f, 0.f, 0.f, 0.f, 0.f, 0.f, 0.f, 0.f};
#pragma unroll
    for (int j = 0; j < 4; ++j) {
        float4 v = *(const float4*)(row + j * 4);
        sq[(j * 4 + 0) & 7] += v.x * v.x;
        sq[(j * 4 + 1) & 7] += v.y * v.y;
        sq[(j * 4 + 2) & 7] += v.z * v.z;
        sq[(j * 4 + 3) & 7] += v.w * v.w;
    }
#pragma unroll
    for (int k = 0; k < 8; ++k) {
        float v = sq[k];
        v += __shfl_xor(v, 1);  v += __shfl_xor(v, 2);  v += __shfl_xor(v, 4);
        v += __shfl_xor(v, 8);  v += __shfl_xor(v, 16); v += __shfl_xor(v, 32);
        sq[k] = v;
    }
    int lane = t & 63, wv = t >> 6;
    if (lane == 0) {
#pragma unroll
        for (int k = 0; k < 8; ++k) red[wv][k] = sq[k];
    }
    __syncthreads();
    if (t < 8) {
        float s = red[0][t] + red[1][t] + red[2][t] + red[3][t];
        inv_norm[b * 8 + t] = 1.0f / sqrtf(s);
    }
}

// ---------------------------------------------------------------------------
// 7) P kernel: P[b][n][k] = (node_h[b] @ q_e[b])[n][k] * inv_norm[b][k]
//    One block per batch (64 blocks x 256 thr = 4 waves); wave w owns rows
//    w*16..w*16+16. MFMA 16x16x32: M=64, N=16 (8 used), K=512 -> 16 MFMAs
//    per wave. A = node_h fp32 -> bf16 in-reg; B from q_h staged in LDS.
__global__ __launch_bounds__(256) void p_k(const float* __restrict__ node_h,
                                           const float* __restrict__ q_h,
                                           const float* __restrict__ inv_norm,
                                           float* __restrict__ P) {
    __shared__ float qs[4096];
    int b = blockIdx.x, t = threadIdx.x;
    int lane = t & 63, w = t >> 6;
    int l15 = lane & 15, l16 = lane >> 4;

    const float* qb = q_h + (size_t)b * 4096;
#pragma unroll
    for (int j = 0; j < 4; ++j)
        *(f32x4*)(&qs[j * 1024 + t * 4]) = *(const f32x4*)(qb + j * 1024 + t * 4);
    __syncthreads();

    bool active = l15 < 8;
    float inv = active ? inv_norm[b * 8 + l15] : 0.f;

    const float* arow = node_h + (size_t)(b * 64 + w * 16 + l15) * 512 + l16 * 8;
    f32x4 acc = (f32x4){0.f, 0.f, 0.f, 0.f};

#pragma unroll
    for (int kt = 0; kt < 16; ++kt) {
        f32x4 v0 = *(const f32x4*)(arow + kt * 32);
        f32x4 v1 = *(const f32x4*)(arow + kt * 32 + 4);
        bf16x8 af = pk8(v0, v1);
        union { unsigned short us[8]; bf16x8 v; } bq;
#pragma unroll
        for (int i = 0; i < 8; ++i)
            bq.us[i] = active ? f2bf(qs[kt * 256 + (l16 * 8 + i) * 8 + l15]) : 0;
        acc = __builtin_amdgcn_mfma_f32_16x16x32_bf16(af, bq.v, acc, 0, 0, 0);
    }

    // D: col=lane&15 (= ks, <8 used), row = w*16 + (lane>>4)*4 + j
    if (active) {
#pragma unroll
        for (int j = 0; j < 4; ++j)
            P[(size_t)(b * 64 + w * 16 + l16 * 4 + j) * 8 + l15] = acc[j] * inv;
    }
}

// ---------------------------------------------------------------------------
// 8) edge kernel: out[m] = P[b][src] + P[b][dst]   (32B gather-add)
__global__ __launch_bounds__(256) void edge2(const int* __restrict__ idxs,
                                             const float* __restrict__ P,
                                             float* __restrict__ out) {
    int m = blockIdx.x * 256 + threadIdx.x;   // 32768 threads
    int idx = idxs[m];
    int b = idx >> 12;                        // idx / (N*N)
    int r = idx & 4095;
    int src = r >> 6, dst = r & 63;
    const float* ps = P + (size_t)(b * 64 + src) * 8;
    const float* pd = P + (size_t)(b * 64 + dst) * 8;
    f32x4 o0 = *(const f32x4*)(ps)     + *(const f32x4*)(pd);
    f32x4 o1 = *(const f32x4*)(ps + 4) + *(const f32x4*)(pd + 4);
    *(f32x4*)(out + (size_t)m * 8)     = o0;
    *(f32x4*)(out + (size_t)m * 8 + 4) = o1;
}

// ---------------------------------------------------------------------------
extern "C" void kernel_launch(void* const* d_in, const int* in_sizes, int n_in,
                              void* d_out, int out_size, void* d_ws, size_t ws_size,
                              hipStream_t stream) {
    const float* node_feats = (const float*)d_in[0];  // [64][64][2048]
    const float* q_feats    = (const float*)d_in[1];  // [64][1024]
    const int*   indexes    = (const int*)d_in[2];    // [32768]
    const float* W_obj      = (const float*)d_in[3];  // [2048][512]
    const float* b_obj      = (const float*)d_in[4];  // [512]
    const float* W_q        = (const float*)d_in[5];  // [1024][4096]
    const float* b_q        = (const float*)d_in[6];  // [4096]
    float* out = (float*)d_out;                       // [32768][8]

    char* ws = (char*)d_ws;
    unsigned short* A_bf16 = (unsigned short*)(ws + 0);        // 16.78MB
    unsigned short* W_T    = (unsigned short*)(ws + 16777216); // 2.10MB
    float* node_h          = (float*)(ws + 18874368);          // 8.39MB fp32
    float* q_h             = (float*)(ws + 27262976);          // 1.05MB
    float* inv_norm        = (float*)(ws + 28311552);          // 2KB
    float* P               = (float*)(ws + 28315648);          // 128KB
    float* part            = (float*)(ws + 0);                 // aliases A_bf16
                                                               // (gemm2 runs after gemm1)

    cvt_a<<<2048, 256, 0, stream>>>(node_feats, A_bf16);
    cvt_bt<<<dim3(64, 16), 256, 0, stream>>>(W_obj, W_T);
    gemm1<<<256, 512, 0, stream>>>(A_bf16, W_T, b_obj, node_h);
    gemm2<<<dim3(32, 8), 256, 0, stream>>>(q_feats, W_q, part);
    finish_q<<<256, 256, 0, stream>>>(part, b_q, q_h);
    norms_k<<<64, 256, 0, stream>>>(q_h, inv_norm);
    p_k<<<64, 256, 0, stream>>>(node_h, q_h, inv_norm, P);
    edge2<<<128, 256, 0, stream>>>(indexes, P, out);
}